// Round 3
// baseline (9641.650 us; speedup 1.0000x reference)
//
#include <hip/hip_runtime.h>

typedef unsigned short u16;
typedef unsigned int u32;
typedef __attribute__((ext_vector_type(4))) float f32x4;
typedef __attribute__((ext_vector_type(8))) short bfrag;   // 8 x bf16 bits
typedef __attribute__((ext_vector_type(8))) unsigned short us8;

// ---------- helpers ----------
__device__ __forceinline__ u16 f2bf(float f) {
    union { float f; unsigned u; } v; v.f = f;
    unsigned r = v.u + 0x7fffu + ((v.u >> 16) & 1u);   // RNE
    return (u16)(r >> 16);
}
__device__ __forceinline__ float sigm(float x) { return 1.0f / (1.0f + __expf(-x)); }
__device__ __forceinline__ float tanh_(float x) { return 1.0f - 2.0f / (__expf(2.0f * x) + 1.0f); }

// ---------- phase A: convert x to bf16 ----------
__global__ __launch_bounds__(256) void pack_x(const float* __restrict__ x, u16* __restrict__ xbf) {
    int gid = blockIdx.x * 256 + threadIdx.x;          // 2,097,152 threads, 8 elems each
    size_t base = (size_t)gid * 8;
    const float4* xv = (const float4*)(x + base);
    float4 a = xv[0], b = xv[1];
    us8 r;
    r[0] = f2bf(a.x); r[1] = f2bf(a.y); r[2] = f2bf(a.z); r[3] = f2bf(a.w);
    r[4] = f2bf(b.x); r[5] = f2bf(b.y); r[6] = f2bf(b.z); r[7] = f2bf(b.w);
    *(us8*)(xbf + base) = r;
}

// ---------- phase A: zero h double-buffers + barrier counters (ws poisoned every call) ----------
__global__ __launch_bounds__(256) void zero_ctl(uint4* __restrict__ p) {
    int gid = blockIdx.x * 256 + threadIdx.x;          // zero 262,656 B = 16,416 uint4
    if (gid < 16416) p[gid] = make_uint4(0u, 0u, 0u, 0u);
}

// ---------- phase A: pack W into MFMA B-fragment layout ----------
// packed[dir][half][ntile(128)][ks(16)][lane(64)][8 bf16]
// element (nt,ks,lane,j) = W[half*512 + ks*32 + (lane>>4)*8 + j][nt*16 + (lane&15)]
__global__ __launch_bounds__(256) void pack_w(const float* __restrict__ Wf, const float* __restrict__ Wb,
                                              u16* __restrict__ wxp, u16* __restrict__ whp) {
    int g = blockIdx.x * 256 + threadIdx.x;            // 524,288 threads
    int lane = g & 63; g >>= 6;
    int ks = g & 15;  g >>= 4;
    int nt = g & 127; g >>= 7;
    int half = g & 1;
    int dir = g >> 1;
    const float* W = dir ? Wb : Wf;
    u16* dst = (half ? whp : wxp) + (size_t)dir * 1048576;
    int rowb = half * 512 + ks * 32 + (lane >> 4) * 8;
    int col  = nt * 16 + (lane & 15);
    us8 v;
#pragma unroll
    for (int j = 0; j < 8; ++j) v[j] = f2bf(W[(size_t)(rowb + j) * 2048 + col]);
    *(us8*)(dst + ((size_t)(nt * 16 + ks) * 64 + lane) * 8) = v;
}

// ---------- phase B: persistent recurrence — fence-free, L3-coherent h exchange ----------
// 64 blocks: dir = bid>>5, j = bid&31 (h-cols [j*16, j*16+16)). Wave w = batch rows [w*16,+16).
// Weights stream from global (L2-hot: 128 KB/block, re-read each step — never invalidated
// because there are NO cache-flushing fences). h double-buffer is exchanged via sc0 sc1
// (L1+L2-bypass) loads/stores: both sides talk straight to the L3 coherence point, so the
// per-direction barrier is: __syncthreads (vmcnt drain) + relaxed device-scope atomic + spin.
__global__ __launch_bounds__(256, 1) void rnn_all(const u16* __restrict__ wxp, const u16* __restrict__ whp,
                                                  const u16* __restrict__ xbf,
                                                  const float* __restrict__ b_fw, const float* __restrict__ b_bw,
                                                  u16* __restrict__ hbuf, unsigned* __restrict__ ctrl,
                                                  float* __restrict__ out) {
    const int tid = threadIdx.x;
    const int bid = blockIdx.x;
    const int dir = bid >> 5, j = bid & 31;
    const int widx = tid >> 6, lane = tid & 63, l15 = lane & 15, lhi = lane >> 4;
    const int m0 = widx * 16;
    const u16* wxs = wxp + (size_t)dir * 1048576;
    const u16* whs = whp + (size_t)dir * 1048576;
    const float* bias = dir ? b_bw : b_fw;
    float bv[4];
#pragma unroll
    for (int g = 0; g < 4; ++g) bv[g] = bias[g * 512 + j * 16 + l15];

    const u16* xb = xbf + (size_t)(m0 + l15) * 262144 + lhi * 8;   // x[b][t][k]
    u16* hb_base = hbuf + (size_t)dir * 65536;                      // 2 phases x 32768 u16
    unsigned* cnt = ctrl + 32 + dir * 32;

    float c[4] = {0.f, 0.f, 0.f, 0.f};
    const int row = m0 + lhi * 4;           // first of 4 batch rows this thread finalizes
    const int hcol = j * 16 + l15;
    float* outb = out + (size_t)row * 524288 + dir * 512 + hcol;    // + r*524288 + t*1024

#pragma unroll 1
    for (int s = 0; s < 512; ++s) {
        const int t = dir ? (511 - s) : s;

        // 1. issue h_{t-1} loads straight from L3 (sc0 sc1 = bypass L1+L2)
        const u16* hb = hb_base + (s & 1) * 32768 + (size_t)(m0 + l15) * 512 + lhi * 8;
        bfrag ah[16];
#pragma unroll
        for (int ks = 0; ks < 16; ++ks)
            asm volatile("global_load_dwordx4 %0, %1, off offset:%2 sc0 sc1"
                         : "=&v"(ah[ks]) : "v"(hb), "i"(ks * 64));

        // 2. x-part (compiler-scheduled; weight/x loads are plain -> L1/L2-cached)
        f32x4 acc[4];
#pragma unroll
        for (int g = 0; g < 4; ++g) acc[g] = (f32x4){bv[g], bv[g], bv[g], bv[g]};
        const u16* xt = xb + t * 512;
#pragma unroll
        for (int ks = 0; ks < 16; ++ks) {
            bfrag ax = *(const bfrag*)(xt + ks * 32);
#pragma unroll
            for (int g = 0; g < 4; ++g)
                acc[g] = __builtin_amdgcn_mfma_f32_16x16x32_bf16(
                    ax, *(const bfrag*)&wxs[(size_t)(g * 32 + j) * 8192 + ks * 512 + lane * 8], acc[g], 0, 0, 0);
        }

        // 3. h loads retired, then h-part (rule #18: waitcnt + sched_barrier before use)
        asm volatile("s_waitcnt vmcnt(0)" ::: "memory");
        __builtin_amdgcn_sched_barrier(0);
#pragma unroll
        for (int ks = 0; ks < 16; ++ks)
#pragma unroll
            for (int g = 0; g < 4; ++g)
                acc[g] = __builtin_amdgcn_mfma_f32_16x16x32_bf16(
                    ah[ks], *(const bfrag*)&whs[(size_t)(g * 32 + j) * 8192 + ks * 512 + lane * 8], acc[g], 0, 0, 0);

        // 4. finalize gates i,j,f,o = acc[0..3]; h stores write-through to L3 (sc0 sc1)
        u16* hw = hb_base + ((s & 1) ^ 1) * 32768 + (size_t)row * 512 + hcol;
#pragma unroll
        for (int r = 0; r < 4; ++r) {
            float cn = sigm(acc[2][r] + 1.0f) * c[r] + sigm(acc[0][r]) * tanh_(acc[1][r]);
            c[r] = cn;
            float h = sigm(acc[3][r]) * tanh_(cn);
            u32 hbits = f2bf(h);
            asm volatile("global_store_short %0, %1, off offset:%2 sc0 sc1"
                         :: "v"(hw), "v"(hbits), "i"(r * 1024) : "memory");
            asm volatile("global_store_dword %0, %1, off sc0 sc1"
                         :: "v"(outb + (size_t)r * 524288 + t * 1024), "v"(h) : "memory");
        }
        if (s == 511) break;

        // 5. per-direction barrier: drain stores (syncthreads waits vmcnt(0)), then
        //    monotonic device-scope counter. No cache fences needed: h went via L3.
        __syncthreads();
        if (tid == 0) {
            __hip_atomic_fetch_add(cnt, 1u, __ATOMIC_RELAXED, __HIP_MEMORY_SCOPE_AGENT);
            const unsigned target = 32u * (unsigned)(s + 1);
            while (__hip_atomic_load(cnt, __ATOMIC_RELAXED, __HIP_MEMORY_SCOPE_AGENT) < target)
                __builtin_amdgcn_s_sleep(1);
        }
        __builtin_amdgcn_s_barrier();        // raw: no vmem drain on re-entry
        __builtin_amdgcn_sched_barrier(0);   // pin next step's h loads below the barrier
    }
}

// ---------- launcher ----------
extern "C" void kernel_launch(void* const* d_in, const int* in_sizes, int n_in,
                              void* d_out, int out_size, void* d_ws, size_t ws_size,
                              hipStream_t stream) {
    (void)in_sizes; (void)n_in; (void)out_size;
    const float* x  = (const float*)d_in[0];
    const float* Wf = (const float*)d_in[1];
    const float* bf = (const float*)d_in[2];
    const float* Wb = (const float*)d_in[3];
    const float* bb = (const float*)d_in[4];
    float* out = (float*)d_out;

    // workspace layout (bytes), total 42,205,696
    const size_t o_wx  = 0;                    //  4,194,304  packed W_x (2 dirs)
    const size_t o_wh  = 4194304;              //  4,194,304  packed W_h (2 dirs)
    const size_t o_hb  = 8388608;              //    262,144  h double buffers (2 dirs x 2)
    const size_t o_ct  = 8650752;              //        512  barrier counters
    const size_t o_xbf = 8651264;              // 33,554,432  x in bf16
    const size_t need  = o_xbf + 33554432;
    if (ws_size < need) return;

    char* ws = (char*)d_ws;
    u16* wxp = (u16*)(ws + o_wx);
    u16* whp = (u16*)(ws + o_wh);
    u16* hb  = (u16*)(ws + o_hb);
    unsigned* ctl = (unsigned*)(ws + o_ct);
    u16* xbf = (u16*)(ws + o_xbf);

    hipLaunchKernelGGL(pack_x, dim3(8192), dim3(256), 0, stream, x, xbf);
    hipLaunchKernelGGL(zero_ctl, dim3(65), dim3(256), 0, stream, (uint4*)(ws + o_hb));
    hipLaunchKernelGGL(pack_w, dim3(2048), dim3(256), 0, stream, Wf, Wb, wxp, whp);
    hipLaunchKernelGGL(rnn_all, dim3(64), dim3(256), 0, stream,
                       wxp, whp, xbf, bf, bb, hb, ctl, out);
}

// Round 4
// 8363.640 us; speedup vs baseline: 1.1528x; 1.1528x over previous
//
#include <hip/hip_runtime.h>

typedef unsigned short u16;
typedef unsigned int u32;
typedef __attribute__((ext_vector_type(4))) float f32x4;
typedef __attribute__((ext_vector_type(8))) short bfrag;   // 8 x bf16 bits
typedef __attribute__((ext_vector_type(8))) unsigned short us8;

// ---------- helpers ----------
__device__ __forceinline__ u16 f2bf(float f) {
    union { float f; unsigned u; } v; v.f = f;
    unsigned r = v.u + 0x7fffu + ((v.u >> 16) & 1u);   // RNE
    return (u16)(r >> 16);
}
__device__ __forceinline__ float sigm(float x) { return 1.0f / (1.0f + __expf(-x)); }
__device__ __forceinline__ float tanh_(float x) { return 1.0f - 2.0f / (__expf(2.0f * x) + 1.0f); }

// ---------- phase A: convert x to bf16 ----------
__global__ __launch_bounds__(256) void pack_x(const float* __restrict__ x, u16* __restrict__ xbf) {
    int gid = blockIdx.x * 256 + threadIdx.x;          // 2,097,152 threads, 8 elems each
    size_t base = (size_t)gid * 8;
    const float4* xv = (const float4*)(x + base);
    float4 a = xv[0], b = xv[1];
    us8 r;
    r[0] = f2bf(a.x); r[1] = f2bf(a.y); r[2] = f2bf(a.z); r[3] = f2bf(a.w);
    r[4] = f2bf(b.x); r[5] = f2bf(b.y); r[6] = f2bf(b.z); r[7] = f2bf(b.w);
    *(us8*)(xbf + base) = r;
}

// ---------- phase A: zero h double-buffers + flags (ws poisoned every call) ----------
__global__ __launch_bounds__(256) void zero_ctl(uint4* __restrict__ p) {
    int gid = blockIdx.x * 256 + threadIdx.x;          // zero 263,168 B = 16,448 uint4
    if (gid < 16448) p[gid] = make_uint4(0u, 0u, 0u, 0u);
}

// ---------- phase A: pack W into MFMA B-fragment layout ----------
// packed[dir][half][ntile(128)][ks(16)][lane(64)][8 bf16]
// element (nt,ks,lane,j) = W[half*512 + ks*32 + (lane>>4)*8 + j][nt*16 + (lane&15)]
__global__ __launch_bounds__(256) void pack_w(const float* __restrict__ Wf, const float* __restrict__ Wb,
                                              u16* __restrict__ wxp, u16* __restrict__ whp) {
    int g = blockIdx.x * 256 + threadIdx.x;            // 524,288 threads
    int lane = g & 63; g >>= 6;
    int ks = g & 15;  g >>= 4;
    int nt = g & 127; g >>= 7;
    int half = g & 1;
    int dir = g >> 1;
    const float* W = dir ? Wb : Wf;
    u16* dst = (half ? whp : wxp) + (size_t)dir * 1048576;
    int rowb = half * 512 + ks * 32 + (lane >> 4) * 8;
    int col  = nt * 16 + (lane & 15);
    us8 v;
#pragma unroll
    for (int j = 0; j < 8; ++j) v[j] = f2bf(W[(size_t)(rowb + j) * 2048 + col]);
    *(us8*)(dst + ((size_t)(nt * 16 + ks) * 64 + lane) * 8) = v;
}

// ---------- phase B: wave-autonomous recurrence, flag-synced, agent-scope (L3) h exchange ----------
// 256 blocks x 64 threads (1 wave each): bid = dir(1) x w(2: batch rows [16w,+16)) x j(5: hcols [16j,+16)).
// Wave (dir,w,j) consumes h rows [16w,+16) (produced only by waves (dir,*,w)); syncs via 32 monotonic
// flags flag[dir][w][*]; publishes flag[dir][w][j]=s+1 after vmcnt(0)-drained sc1 h stores.
// No barriers, no fences, no atomic RMW in the steady loop. Weights stream from L1/L2 (never flushed).
__global__ __launch_bounds__(64, 1) void rnn_all(const u16* __restrict__ wxp, const u16* __restrict__ whp,
                                                 const u16* __restrict__ xbf,
                                                 const float* __restrict__ b_fw, const float* __restrict__ b_bw,
                                                 u16* __restrict__ hbuf, unsigned* __restrict__ ctrl,
                                                 float* __restrict__ out) {
    const int lane = threadIdx.x & 63;
    const int bid = blockIdx.x;
    const int dir = bid >> 7, w = (bid >> 5) & 3, j = bid & 31;
    const int l15 = lane & 15, lhi = lane >> 4;
    const int m0 = w * 16;
    const u16* wxs = wxp + (size_t)dir * 1048576;
    const u16* whs = whp + (size_t)dir * 1048576;
    const float* bias = dir ? b_bw : b_fw;
    float bv[4];
#pragma unroll
    for (int g = 0; g < 4; ++g) bv[g] = bias[g * 512 + j * 16 + l15];

    const u16* xb = xbf + (size_t)(m0 + l15) * 262144 + lhi * 8;   // x[b][t][k]
    u16* hb_base = hbuf + (size_t)dir * 65536;                      // 2 phases x 32768 u16
    unsigned* flagw = ctrl + dir * 128 + w * 32;                    // my row-group's producer flags

    float c[4] = {0.f, 0.f, 0.f, 0.f};
    const int row = m0 + lhi * 4;            // first of 4 batch rows this thread finalizes
    const int hcol = j * 16 + l15;
    float* outb = out + (size_t)row * 524288 + dir * 512 + hcol;    // + r*524288 + t*1024
    const size_t hread = (size_t)(m0 + l15) * 512 + lhi * 8;

    // prologue: acc = bias + x-part(t0)
    f32x4 acc[4];
#pragma unroll
    for (int g = 0; g < 4; ++g) acc[g] = (f32x4){bv[g], bv[g], bv[g], bv[g]};
    {
        const u16* xt = xb + (dir ? 511 : 0) * 512;
#pragma unroll
        for (int ks = 0; ks < 16; ++ks) {
            bfrag ax = *(const bfrag*)(xt + ks * 32);
#pragma unroll
            for (int g = 0; g < 4; ++g)
                acc[g] = __builtin_amdgcn_mfma_f32_16x16x32_bf16(
                    ax, *(const bfrag*)&wxs[(size_t)(g * 32 + j) * 8192 + ks * 512 + lane * 8], acc[g], 0, 0, 0);
        }
    }

#pragma unroll 1
    for (int s = 0; s < 512; ++s) {
        const int t = dir ? (511 - s) : s;

        // 1. wait until all 32 producers of my row-group published h(s-1)
        if (s) {
            unsigned f;
            do {
                f = 0xffffffffu;
                if (lane < 32)
                    f = __hip_atomic_load(&flagw[lane], __ATOMIC_RELAXED, __HIP_MEMORY_SCOPE_AGENT);
            } while (__any((int)(f < (unsigned)s)));
        }

        // 2. h(s-1) loads, agent scope (served by L3; producers wrote through with sc1)
        const u16* hbp = hb_base + (s & 1) * 32768 + hread;
        bfrag ah[16];
#pragma unroll
        for (int ks = 0; ks < 16; ++ks)
            asm volatile("global_load_dwordx4 %0, %1, off offset:%2 sc1"
                         : "=&v"(ah[ks]) : "v"(hbp), "i"(ks * 64) : "memory");
        asm volatile("s_waitcnt vmcnt(0)" ::: "memory");
        __builtin_amdgcn_sched_barrier(0);

        // 3. h-part MFMAs (Wh B-fragments stream from L1/L2, never invalidated)
#pragma unroll
        for (int ks = 0; ks < 16; ++ks)
#pragma unroll
            for (int g = 0; g < 4; ++g)
                acc[g] = __builtin_amdgcn_mfma_f32_16x16x32_bf16(
                    ah[ks], *(const bfrag*)&whs[(size_t)(g * 32 + j) * 8192 + ks * 512 + lane * 8], acc[g], 0, 0, 0);

        // 4. finalize gates i,j,f,o = acc[0..3]; write-through h (sc1 -> L3)
        u16* hw = hb_base + ((s & 1) ^ 1) * 32768 + (size_t)row * 512 + hcol;
        float hv[4];
#pragma unroll
        for (int r = 0; r < 4; ++r) {
            float cn = sigm(acc[2][r] + 1.0f) * c[r] + sigm(acc[0][r]) * tanh_(acc[1][r]);
            c[r] = cn;
            float h = sigm(acc[3][r]) * tanh_(cn);
            hv[r] = h;
            u32 hb16 = f2bf(h);
            asm volatile("global_store_short %0, %1, off offset:%2 sc1"
                         :: "v"(hw), "v"(hb16), "i"(r * 1024) : "memory");
        }

        // 5. publish: drain own h stores (at L3), then monotonic flag (asm => no sinking)
        if (s < 511) {
            asm volatile("s_waitcnt vmcnt(0)" ::: "memory");
            if (lane == 0) {
                unsigned fv = (unsigned)(s + 1);
                asm volatile("global_store_dword %0, %1, off sc1"
                             :: "v"(flagw + j), "v"(fv) : "memory");
            }
        }

        // 6. out stores (plain, write-back, off the critical path)
#pragma unroll
        for (int r = 0; r < 4; ++r)
            outb[(size_t)r * 524288 + t * 1024] = hv[r];

        // 7. x-part for next step — overlaps other waves' consumption of our h(s)
        if (s < 511) {
            const int tn = dir ? (510 - s) : (s + 1);
#pragma unroll
            for (int g = 0; g < 4; ++g) acc[g] = (f32x4){bv[g], bv[g], bv[g], bv[g]};
            const u16* xt = xb + tn * 512;
#pragma unroll
            for (int ks = 0; ks < 16; ++ks) {
                bfrag ax = *(const bfrag*)(xt + ks * 32);
#pragma unroll
                for (int g = 0; g < 4; ++g)
                    acc[g] = __builtin_amdgcn_mfma_f32_16x16x32_bf16(
                        ax, *(const bfrag*)&wxs[(size_t)(g * 32 + j) * 8192 + ks * 512 + lane * 8], acc[g], 0, 0, 0);
            }
        }
    }
}

// ---------- launcher ----------
extern "C" void kernel_launch(void* const* d_in, const int* in_sizes, int n_in,
                              void* d_out, int out_size, void* d_ws, size_t ws_size,
                              hipStream_t stream) {
    (void)in_sizes; (void)n_in; (void)out_size;
    const float* x  = (const float*)d_in[0];
    const float* Wf = (const float*)d_in[1];
    const float* bf = (const float*)d_in[2];
    const float* Wb = (const float*)d_in[3];
    const float* bb = (const float*)d_in[4];
    float* out = (float*)d_out;

    // workspace layout (bytes), total 42,209,280
    const size_t o_wx  = 0;                    //  4,194,304  packed W_x (2 dirs)
    const size_t o_wh  = 4194304;              //  4,194,304  packed W_h (2 dirs)
    const size_t o_hb  = 8388608;              //    262,144  h double buffers (2 dirs x 2)
    const size_t o_ct  = 8650752;              //      1,024  flags [dir][w][j] (+pad)
    const size_t o_xbf = 8654848;              // 33,554,432  x in bf16
    const size_t need  = o_xbf + 33554432;
    if (ws_size < need) return;

    char* ws = (char*)d_ws;
    u16* wxp = (u16*)(ws + o_wx);
    u16* whp = (u16*)(ws + o_wh);
    u16* hb  = (u16*)(ws + o_hb);
    unsigned* ctl = (unsigned*)(ws + o_ct);
    u16* xbf = (u16*)(ws + o_xbf);

    hipLaunchKernelGGL(pack_x, dim3(8192), dim3(256), 0, stream, x, xbf);
    hipLaunchKernelGGL(zero_ctl, dim3(65), dim3(256), 0, stream, (uint4*)(ws + o_hb));
    hipLaunchKernelGGL(pack_w, dim3(2048), dim3(256), 0, stream, Wf, Wb, wxp, whp);
    hipLaunchKernelGGL(rnn_all, dim3(256), dim3(64), 0, stream,
                       wxp, whp, xbf, bf, bb, hb, ctl, out);
}